// Round 1
// 488.702 us; speedup vs baseline: 1.3185x; 1.3185x over previous
//
#include <hip/hip_runtime.h>

typedef unsigned short u16;
typedef unsigned int u32;
typedef unsigned long long u64;

#define T_ 4
#define N_ 20000
#define E_ 640000
#define DIN 256
#define DOUT 128
#define NT (T_*N_)          // 80000
#define TE (T_*E_)          // 2560000
#define SLOPE 0.22916666666666666f

// coarse binning geometry: 125 buckets of 160 nodes per timestep
#define NB 125
#define BNODES 160
#define CAP 5632            // mean 5120, sigma ~72 -> 14 sigma headroom
#define NBTOT (T_*NB)       // 500

typedef __attribute__((ext_vector_type(8))) short short8;
typedef __attribute__((ext_vector_type(4))) float f32x4;

__device__ __forceinline__ float blo(u32 u) { return __uint_as_float(u << 16); }
__device__ __forceinline__ float bhi(u32 u) { return __uint_as_float(u & 0xFFFF0000u); }
__device__ __forceinline__ u16 f2bf(float f) {
    u32 u = __float_as_uint(f);
    return (u16)((u + 0x7FFFu + ((u >> 16) & 1u)) >> 16);
}
__device__ __forceinline__ u32 fkey(float f) {
    u32 u = __float_as_uint(f);
    return (u & 0x80000000u) ? ~u : (u | 0x80000000u);
}
__device__ __forceinline__ float fkeyinv(u32 k) {
    u32 u = (k & 0x80000000u) ? (k ^ 0x80000000u) : ~k;
    return __uint_as_float(u);
}

// ---------------- transpose+pack the 6 GRU weight matrices (f32 -> bf16 pairs) ------
__global__ void k_transpose(const float* Wz, const float* Uz, const float* Wr, const float* Ur,
                            const float* Wh, const float* Uh, u32* Tp) {
    int bid = blockIdx.x;
    int m = bid >> 7, b = bid & 127;
    int idx = b * 256 + threadIdx.x;      // 0..32767
    int d2 = idx & 127, i = idx >> 7;     // coalesced f32 pair reads
    const float* src;
    switch (m) {
        case 0: src = Wz; break;
        case 1: src = Uz; break;
        case 2: src = Wr; break;
        case 3: src = Ur; break;
        case 4: src = Wh; break;
        default: src = Uh; break;
    }
    float lo = src[i * 256 + 2 * d2];
    float hi = src[i * 256 + 2 * d2 + 1];
    Tp[m * 32768 + d2 * 256 + i] = (u32)f2bf(lo) | ((u32)f2bf(hi) << 16);
}

// ---------------- scores: (x.p)/||p|| + mask, plus x -> bf16 conversion ----------------
__global__ __launch_bounds__(256) void k_scores(const float* x, const float* p, const float* mask,
                                                float* scores, u16* xb16) {
    __shared__ float pl[256];
    __shared__ float s_invn;
    int tid = threadIdx.x;
    pl[tid] = p[tid];
    __syncthreads();
    if (tid < 64) {
        float v = pl[tid] * pl[tid] + pl[tid + 64] * pl[tid + 64] +
                  pl[tid + 128] * pl[tid + 128] + pl[tid + 192] * pl[tid + 192];
        for (int o = 32; o > 0; o >>= 1) v += __shfl_xor(v, o);
        if (tid == 0) s_invn = 1.0f / sqrtf(v);
    }
    __syncthreads();
    int wid = tid >> 6, lane = tid & 63;
    for (int it = 0; it < 4; ++it) {
        int node = blockIdx.x * 16 + wid * 4 + it;   // 5000*16 == 80000
        const float* row = x + (size_t)node * DIN + lane * 4;
        float4 u = *(const float4*)row;
        float d = u.x * pl[lane * 4 + 0] + u.y * pl[lane * 4 + 1] +
                  u.z * pl[lane * 4 + 2] + u.w * pl[lane * 4 + 3];
        u32 p0 = (u32)f2bf(u.x) | ((u32)f2bf(u.y) << 16);
        u32 p1 = (u32)f2bf(u.z) | ((u32)f2bf(u.w) << 16);
        *(uint2*)(xb16 + (size_t)node * DIN + lane * 4) = make_uint2(p0, p1);
        for (int o = 32; o > 0; o >>= 1) d += __shfl_xor(d, o);
        if (lane == 0) scores[node] = d * s_invn + mask[node];
    }
}

// ---------------- phase 1: LDS-staged coarse binning (replaces k_count + k_place) ------
// Pack: bits [0,17) = t*N+src, [17,25) = dstLocal (0..159), [25,32) = bucket (0..124)
__global__ __launch_bounds__(256) void k_bin(const int* ei, const float* ew,
                                             int* gcur, uint2* binned) {
    int blk = blockIdx.x;                // 0..999
    int t = blk / 250, ci = blk - t * 250;
    int ebase = ci * 2560;
    int tid = threadIdx.x;
    __shared__ u32 hist[128], sc[128], gbase[128];
    __shared__ uint2 stage[2560];
    if (tid < 128) hist[tid] = 0;
    __syncthreads();
    u32 px[10]; u32 pw[10]; u16 rk[10];
#pragma unroll
    for (int k = 0; k < 10; ++k) {
        int e = ebase + tid + k * 256;                  // < E_ exactly
        int dst = ei[t * (2 * E_) + e];
        int src = ei[t * (2 * E_) + E_ + e];
        float w = ew[t * E_ + e];
        int b = dst / BNODES;                           // 0..124
        int dl = dst - b * BNODES;                      // 0..159
        px[k] = (u32)(t * N_ + src) | ((u32)dl << 17) | ((u32)b << 25);
        pw[k] = __float_as_uint(w);
        rk[k] = (u16)atomicAdd(&hist[b], 1u);
    }
    __syncthreads();
    // inclusive scan of hist (125 live, padded to 128)
    if (tid < 128) sc[tid] = hist[tid];
    __syncthreads();
    for (int o = 1; o < 128; o <<= 1) {
        u32 v = 0;
        if (tid < 128) { v = sc[tid]; if (tid >= o) v += sc[tid - o]; }
        __syncthreads();
        if (tid < 128) sc[tid] = v;
        __syncthreads();
    }
    // reserve contiguous global runs (one atomic per bucket per block)
    if (tid < NB) gbase[tid] = (u32)atomicAdd(&gcur[t * NB + tid], (int)hist[tid]);
    // stage into bucket-sorted LDS order: slot = exclusiveStart(b) + rank
#pragma unroll
    for (int k = 0; k < 10; ++k) {
        int b = px[k] >> 25;
        u32 slot = (sc[b] - hist[b]) + rk[k];
        stage[slot] = make_uint2(px[k], pw[k]);
    }
    __syncthreads();
    // flush: consecutive slots -> consecutive global addresses within each bucket run
    for (int s = tid; s < 2560; s += 256) {
        uint2 v = stage[s];
        int b = v.x >> 25;
        u32 local = gbase[b] + ((u32)s - (sc[b] - hist[b]));
        if (local < CAP)
            binned[(size_t)(t * NB + b) * CAP + local] = v;
    }
}

// ---------------- phase 2: in-place per-bucket sort by node + offsets + zero padding ---
__global__ __launch_bounds__(512) void k_scatter(const int* gcur, uint2* binned, int* offsets) {
    int bg = blockIdx.x;                 // 0..499
    int t = bg / NB, bl = bg - t * NB;
    uint2* bucket = binned + (size_t)bg * CAP;
    int cnt = gcur[bg]; if (cnt > CAP) cnt = CAP;
    int tid = threadIdx.x;
    __shared__ u32 nhist[256], sc2[256], nstart[BNODES];
    if (tid < 256) nhist[tid] = 0;
    __syncthreads();
    u32 vx[11]; u32 vw[11]; u16 r_[11];
#pragma unroll
    for (int k = 0; k < 11; ++k) {       // 11*512 = 5632 = CAP
        int e = tid + k * 512;
        r_[k] = 0xFFFFu;
        if (e < cnt) {
            uint2 v = bucket[e];
            vx[k] = v.x; vw[k] = v.y;
            int dl = (v.x >> 17) & 255;
            r_[k] = (u16)atomicAdd(&nhist[dl], 1u);
        }
    }
    __syncthreads();
    if (tid < 256) sc2[tid] = nhist[tid];
    __syncthreads();
    for (int o = 1; o < 256; o <<= 1) {
        u32 v = 0;
        if (tid < 256) { v = sc2[tid]; if (tid >= o) v += sc2[tid - o]; }
        __syncthreads();
        if (tid < 256) sc2[tid] = v;
        __syncthreads();
    }
    if (tid < BNODES) {
        u32 st = sc2[tid] - nhist[tid];
        nstart[tid] = st;
        offsets[t * N_ + bl * BNODES + tid] = bg * CAP + (int)st;
    }
    if (bg == NBTOT - 1 && tid == 0) offsets[NT] = NBTOT * CAP;
    __syncthreads();
#pragma unroll
    for (int k = 0; k < 11; ++k) {
        if (r_[k] != 0xFFFFu) {
            int dl = (vx[k] >> 17) & 255;
            u32 pos = nstart[dl] + r_[k];               // < cnt <= CAP
            bucket[pos] = make_uint2(vx[k] & 0x1FFFFu, vw[k]);
        }
    }
    // pad to capacity with zero-weight edges so offsets stay monotone through bucket ends
    for (int s = cnt + tid; s < CAP; s += 512) bucket[s] = make_uint2(0u, 0u);
}

// ---------------- top-128 (radix select, exact jax order) + xtT build ----------------
__global__ __launch_bounds__(1024) void k_topk(const float* scores, const float* x, float* xtT) {
    int t = blockIdx.x;
    int tid = threadIdx.x;   // 0..1023
    const float* sc = scores + t * N_;
    __shared__ u32 hist[256];
    __shared__ u32 sh_dig, sh_need;
    __shared__ u64 sel[256];
    __shared__ u32 selCount;
    __shared__ u32 idxl[128];
    __shared__ float tvl[128];

    u32 kreg[20];
#pragma unroll
    for (int p = 0; p < 20; ++p) {
        int i = tid + p * 1024;
        kreg[p] = (i < N_) ? fkey(sc[i]) : 0u;
    }

    u32 pref = 0;
    u32 need = 128;
    for (int pass = 0; pass < 4; ++pass) {
        int shift = 24 - 8 * pass;
        if (tid < 256) hist[tid] = 0;
        __syncthreads();
#pragma unroll
        for (int p = 0; p < 20; ++p) {
            int i = tid + p * 1024;
            u32 k = kreg[p];
            bool ok = (i < N_) && ((pass == 0) || ((k >> (shift + 8)) == pref));
            if (ok) atomicAdd(&hist[(k >> shift) & 255u], 1u);
        }
        __syncthreads();
        if (tid < 64) {
            int l = tid;
            u32 s = hist[4 * l] + hist[4 * l + 1] + hist[4 * l + 2] + hist[4 * l + 3];
            u32 S = s;
            for (int o = 1; o < 64; o <<= 1) {
                u32 y = __shfl_down(S, o);
                if (l + o < 64) S += y;
            }
            u64 m = __ballot(S >= need);
            int L = 63 - __builtin_clzll(m);
            if (l == L) {
                u32 Snext = S - s;
                u32 r = 0;
                for (int dd = 3; dd >= 0; --dd) {
                    u32 hb = hist[4 * L + dd];
                    r += hb;
                    if (Snext + r >= need) {
                        sh_dig = (u32)(4 * L + dd);
                        sh_need = need - (Snext + r - hb);
                        break;
                    }
                }
            }
        }
        __syncthreads();
        pref = (pref << 8) | sh_dig;
        need = sh_need;
        __syncthreads();
    }
    if (tid == 0) selCount = 0;
    __syncthreads();
    u32 theta = pref;
#pragma unroll
    for (int p = 0; p < 20; ++p) {
        int i = tid + p * 1024;
        u32 k = kreg[p];
        if (i < N_ && k >= theta) {
            u32 pos = atomicAdd(&selCount, 1u);
            if (pos < 256) sel[pos] = (((u64)(k ^ 0xFFFFFFFFu)) << 32) | (u32)i;
        }
    }
    __syncthreads();
    u32 c = selCount;
    if (c > 256) c = 256;
    if (tid < 256 && (u32)tid >= c) sel[tid] = 0xFFFFFFFFFFFFFFFFull;
    __syncthreads();
    // bitonic ascending sort: key = (~fkey)<<32 | idx  -> value desc, idx asc
    for (int k2 = 2; k2 <= 256; k2 <<= 1) {
        for (int jj = k2 >> 1; jj > 0; jj >>= 1) {
            if (tid < 256) {
                int i = tid, ixj = i ^ jj;
                if (ixj > i) {
                    u64 A = sel[i], B = sel[ixj];
                    bool asc = ((i & k2) == 0);
                    bool sw = asc ? (A > B) : (A < B);
                    if (sw) { sel[i] = B; sel[ixj] = A; }
                }
            }
            __syncthreads();
        }
    }
    if (tid < 128) {
        u64 v = sel[tid];
        u32 k = ((u32)(v >> 32)) ^ 0xFFFFFFFFu;
        idxl[tid] = (u32)(v & 0xFFFFFFFFu);
        tvl[tid] = tanhf(fkeyinv(k));
    }
    __syncthreads();
    float* xt_t = xtT + t * (DIN * DOUT);
    const float* xb = x + (size_t)t * N_ * DIN;
    for (int e2 = tid; e2 < DIN * DOUT; e2 += 1024) {
        int j = e2 >> 8, d = e2 & 255;
        xt_t[e2] = xb[(size_t)idxl[j] * DIN + d] * tvl[j];
    }
}

// ---------------- fused matrix-GRU: one block per 2 output columns (j0, j0+64) -------
__global__ __launch_bounds__(256) void k_gru(const float* xtT, const float* WprevT,
                                             const float* W0, int firstT, const u32* Tp,
                                             const float* bz, const float* br, const float* bh,
                                             float* WnextT, u16* WnT_t) {
    int j0 = blockIdx.x;          // 0..63
    int j1 = j0 + 64;
    int i = threadIdx.x;          // 0..255
    __shared__ float sxt[2][256], sW[2][256], srw[2][256];
    sxt[0][i] = xtT[j0 * 256 + i];
    sxt[1][i] = xtT[j1 * 256 + i];
    float wv0 = firstT ? W0[i * 128 + j0] : WprevT[j0 * 256 + i];
    float wv1 = firstT ? W0[i * 128 + j1] : WprevT[j1 * 256 + i];
    sW[0][i] = wv0;
    sW[1][i] = wv1;
    __syncthreads();
    const u32* WzT = Tp;
    const u32* UzT = Tp + 32768;
    const u32* WrT = Tp + 65536;
    const u32* UrT = Tp + 98304;
    const u32* WhT = Tp + 131072;
    const u32* UhT = Tp + 163840;
    float az0 = bz[i * 128 + j0], az1 = bz[i * 128 + j1];
    float ar0 = br[i * 128 + j0], ar1 = br[i * 128 + j1];
#pragma unroll 4
    for (int d2 = 0; d2 < 128; ++d2) {
        float x00 = sxt[0][2 * d2], x01 = sxt[0][2 * d2 + 1];
        float x10 = sxt[1][2 * d2], x11 = sxt[1][2 * d2 + 1];
        float w00 = sW[0][2 * d2], w01 = sW[0][2 * d2 + 1];
        float w10 = sW[1][2 * d2], w11 = sW[1][2 * d2 + 1];
        u32 a = WzT[d2 * 256 + i], b = UzT[d2 * 256 + i];
        u32 cc = WrT[d2 * 256 + i], dd = UrT[d2 * 256 + i];
        az0 += blo(a) * x00 + bhi(a) * x01 + blo(b) * w00 + bhi(b) * w01;
        az1 += blo(a) * x10 + bhi(a) * x11 + blo(b) * w10 + bhi(b) * w11;
        ar0 += blo(cc) * x00 + bhi(cc) * x01 + blo(dd) * w00 + bhi(dd) * w01;
        ar1 += blo(cc) * x10 + bhi(cc) * x11 + blo(dd) * w10 + bhi(dd) * w11;
    }
    float z0 = 1.0f / (1.0f + expf(-az0));
    float z1 = 1.0f / (1.0f + expf(-az1));
    float r0 = 1.0f / (1.0f + expf(-ar0));
    float r1 = 1.0f / (1.0f + expf(-ar1));
    srw[0][i] = r0 * wv0;
    srw[1][i] = r1 * wv1;
    __syncthreads();
    float ah0 = bh[i * 128 + j0], ah1 = bh[i * 128 + j1];
#pragma unroll 4
    for (int d2 = 0; d2 < 128; ++d2) {
        float x00 = sxt[0][2 * d2], x01 = sxt[0][2 * d2 + 1];
        float x10 = sxt[1][2 * d2], x11 = sxt[1][2 * d2 + 1];
        float r00 = srw[0][2 * d2], r01 = srw[0][2 * d2 + 1];
        float r10 = srw[1][2 * d2], r11 = srw[1][2 * d2 + 1];
        u32 a = WhT[d2 * 256 + i], b = UhT[d2 * 256 + i];
        ah0 += blo(a) * x00 + bhi(a) * x01 + blo(b) * r00 + bhi(b) * r01;
        ah1 += blo(a) * x10 + bhi(a) * x11 + blo(b) * r10 + bhi(b) * r11;
    }
    float h0 = tanhf(ah0), h1 = tanhf(ah1);
    float wn0 = (1.0f - z0) * wv0 + z0 * h0;
    float wn1 = (1.0f - z1) * wv1 + z1 * h1;
    WnextT[j0 * 256 + i] = wn0;
    WnextT[j1 * 256 + i] = wn1;
    WnT_t[j0 * 256 + i] = f2bf(wn0);
    WnT_t[j1 * 256 + i] = f2bf(wn1);
}

// ---------------- y = x_bf16 @ Wn (MFMA bf16), batched over t ----------------
__global__ __launch_bounds__(128) void k_gemm(const u16* xb16, const u16* WnT, u16* y) {
    int t = blockIdx.y;
    const u16* xb = xb16 + (size_t)t * N_ * DIN;
    const u16* Bt = WnT + t * (DIN * DOUT);
    u16* yb = y + (size_t)t * N_ * DOUT;
    int wid = threadIdx.x >> 6, lane = threadIdx.x & 63;
    int quad = lane >> 4, lm = lane & 15;
    int rowBase = blockIdx.x * 64 + wid * 32;
    f32x4 acc[2][8];
#pragma unroll
    for (int mi = 0; mi < 2; ++mi)
#pragma unroll
        for (int ni = 0; ni < 8; ++ni) acc[mi][ni] = (f32x4){0.f, 0.f, 0.f, 0.f};
    size_t aoff[2];
#pragma unroll
    for (int mi = 0; mi < 2; ++mi) {
        int r = rowBase + mi * 16 + lm;
        if (r > N_ - 1) r = N_ - 1;
        aoff[mi] = (size_t)r * DIN + quad * 8;
    }
    const u16* bbase = Bt + lm * 256 + quad * 8;
    for (int kk = 0; kk < 256; kk += 32) {
        short8 a0 = *(const short8*)(xb + aoff[0] + kk);
        short8 a1 = *(const short8*)(xb + aoff[1] + kk);
#pragma unroll
        for (int ni = 0; ni < 8; ++ni) {
            short8 b = *(const short8*)(bbase + ni * 4096 + kk);
            acc[0][ni] = __builtin_amdgcn_mfma_f32_16x16x32_bf16(a0, b, acc[0][ni], 0, 0, 0);
            acc[1][ni] = __builtin_amdgcn_mfma_f32_16x16x32_bf16(a1, b, acc[1][ni], 0, 0, 0);
        }
    }
#pragma unroll
    for (int mi = 0; mi < 2; ++mi)
#pragma unroll
        for (int ni = 0; ni < 8; ++ni)
#pragma unroll
            for (int r = 0; r < 4; ++r) {
                int row = rowBase + mi * 16 + quad * 4 + r;
                if (row < N_) yb[(size_t)row * DOUT + ni * 16 + lm] = f2bf(acc[mi][ni][r]);
            }
}

// ---------------- CSR gather-aggregate: 8 edges in flight per wave ----------------
__global__ __launch_bounds__(256) void k_agg(const int* offsets, const uint2* srcw,
                                             const u16* y, float* out) {
    int g = blockIdx.x * 4 + (threadIdx.x >> 6);   // < NT
    int lane = threadIdx.x & 63;
    int q = lane >> 4, lq = lane & 15;
    int o0 = offsets[g], o1 = offsets[g + 1];
    float acc[8];
#pragma unroll
    for (int i = 0; i < 8; ++i) acc[i] = 0.f;
    int e0 = o0;
    for (; e0 + 8 <= o1; e0 += 8) {
        int ea = e0 + q, eb = e0 + 4 + q;
        uint2 ma = srcw[ea];
        uint2 mb = srcw[eb];
        float wa = __uint_as_float(ma.y);
        float wb = __uint_as_float(mb.y);
        uint4 va = *(const uint4*)(y + (size_t)ma.x * DOUT + lq * 8);
        uint4 vb = *(const uint4*)(y + (size_t)mb.x * DOUT + lq * 8);
        acc[0] += wa * blo(va.x); acc[1] += wa * bhi(va.x);
        acc[2] += wa * blo(va.y); acc[3] += wa * bhi(va.y);
        acc[4] += wa * blo(va.z); acc[5] += wa * bhi(va.z);
        acc[6] += wa * blo(va.w); acc[7] += wa * bhi(va.w);
        acc[0] += wb * blo(vb.x); acc[1] += wb * bhi(vb.x);
        acc[2] += wb * blo(vb.y); acc[3] += wb * bhi(vb.y);
        acc[4] += wb * blo(vb.z); acc[5] += wb * bhi(vb.z);
        acc[6] += wb * blo(vb.w); acc[7] += wb * bhi(vb.w);
    }
    for (; e0 < o1; e0 += 4) {
        int e = e0 + q;
        if (e < o1) {
            uint2 m = srcw[e];
            float wv = __uint_as_float(m.y);
            uint4 v = *(const uint4*)(y + (size_t)m.x * DOUT + lq * 8);
            acc[0] += wv * blo(v.x); acc[1] += wv * bhi(v.x);
            acc[2] += wv * blo(v.y); acc[3] += wv * bhi(v.y);
            acc[4] += wv * blo(v.z); acc[5] += wv * bhi(v.z);
            acc[6] += wv * blo(v.w); acc[7] += wv * bhi(v.w);
        }
    }
#pragma unroll
    for (int i = 0; i < 8; ++i) {
        acc[i] += __shfl_xor(acc[i], 16);
        acc[i] += __shfl_xor(acc[i], 32);
        acc[i] = (acc[i] >= 0.f) ? acc[i] : SLOPE * acc[i];
    }
    if (q == 0) {
        float4 v0 = make_float4(acc[0], acc[1], acc[2], acc[3]);
        float4 v1 = make_float4(acc[4], acc[5], acc[6], acc[7]);
        float* ob = out + (size_t)g * DOUT + lq * 8;
        *(float4*)ob = v0;
        *(float4*)(ob + 4) = v1;
    }
}

extern "C" void kernel_launch(void* const* d_in, const int* in_sizes, int n_in,
                              void* d_out, int out_size, void* d_ws, size_t ws_size,
                              hipStream_t stream) {
    const float* x = (const float*)d_in[0];
    const int* ei = (const int*)d_in[1];
    const float* ew = (const float*)d_in[2];
    const float* mask = (const float*)d_in[3];
    const float* p = (const float*)d_in[4];
    const float* Wz = (const float*)d_in[5];
    const float* Uz = (const float*)d_in[6];
    const float* bz = (const float*)d_in[7];
    const float* Wr = (const float*)d_in[8];
    const float* Ur = (const float*)d_in[9];
    const float* br = (const float*)d_in[10];
    const float* Wh = (const float*)d_in[11];
    const float* Uh = (const float*)d_in[12];
    const float* bh = (const float*)d_in[13];
    const float* W0 = (const float*)d_in[14];
    float* out = (float*)d_out;

    char* w = (char*)d_ws;
    u16* xb16 = (u16*)w;        w += (size_t)NT * DIN * 2;        // 40,960,000
    float* scores = (float*)w;  w += 320256;                      // NT f32
    float* xtT = (float*)w;     w += 4 * 32768 * 4;               // [t][128][256] f32
    float* Wst = (float*)w;     w += 2 * 32768 * 4;               // ping-pong W^T state f32
    u16* WnT = (u16*)w;         w += 4 * 32768 * 2;               // [t][128][256] bf16
    u32* Tp = (u32*)w;          w += 6 * 32768 * 4;               // packed transposed weights
    u16* y = (u16*)w;           w += (size_t)NT * DOUT * 2;       // [t][N][128] bf16
    uint2* binned = (uint2*)w;  w += (size_t)NBTOT * CAP * 8;     // bucketed edges -> final CSR (in place)
    int* gcur = (int*)w;        w += 2048;                        // 500 bucket cursors
    int* offsets = (int*)w;     w += 320256;                      // NT+1

    hipMemsetAsync(gcur, 0, 2048, stream);

    k_transpose<<<768, 256, 0, stream>>>(Wz, Uz, Wr, Ur, Wh, Uh, Tp);
    k_scores<<<5000, 256, 0, stream>>>(x, p, mask, scores, xb16);
    k_bin<<<1000, 256, 0, stream>>>(ei, ew, gcur, binned);
    k_scatter<<<NBTOT, 512, 0, stream>>>(gcur, binned, offsets);
    k_topk<<<4, 1024, 0, stream>>>(scores, x, xtT);

    for (int t = 0; t < 4; ++t) {
        const float* WprevT = (t == 0) ? Wst : (Wst + ((t + 1) & 1) * 32768);
        float* WnextT = Wst + (t & 1) * 32768;
        k_gru<<<64, 256, 0, stream>>>(xtT + t * 32768, WprevT, W0, (t == 0) ? 1 : 0, Tp,
                                      bz, br, bh, WnextT, WnT + t * 32768);
    }
    k_gemm<<<dim3(313, 4), 128, 0, stream>>>(xb16, WnT, y);
    k_agg<<<N_, 256, 0, stream>>>(offsets, binned, y, out);
}

// Round 2
// 472.306 us; speedup vs baseline: 1.3643x; 1.0347x over previous
//
#include <hip/hip_runtime.h>

typedef unsigned short u16;
typedef unsigned int u32;
typedef unsigned long long u64;

#define T_ 4
#define N_ 20000
#define E_ 640000
#define DIN 256
#define DOUT 128
#define NT (T_*N_)          // 80000
#define TE (T_*E_)          // 2560000
#define SLOPE 0.22916666666666666f

// coarse binning geometry: 125 buckets of 160 nodes per timestep
#define NB 125
#define BNODES 160
#define CAP 5632            // mean 5120, sigma ~72 -> 14 sigma headroom
#define NBTOT (T_*NB)       // 500

typedef __attribute__((ext_vector_type(8))) short short8;
typedef __attribute__((ext_vector_type(4))) float f32x4;

__device__ __forceinline__ float blo(u32 u) { return __uint_as_float(u << 16); }
__device__ __forceinline__ float bhi(u32 u) { return __uint_as_float(u & 0xFFFF0000u); }
__device__ __forceinline__ u16 f2bf(float f) {
    u32 u = __float_as_uint(f);
    return (u16)((u + 0x7FFFu + ((u >> 16) & 1u)) >> 16);
}
__device__ __forceinline__ u32 fkey(float f) {
    u32 u = __float_as_uint(f);
    return (u & 0x80000000u) ? ~u : (u | 0x80000000u);
}
__device__ __forceinline__ float fkeyinv(u32 k) {
    u32 u = (k & 0x80000000u) ? (k ^ 0x80000000u) : ~k;
    return __uint_as_float(u);
}

// ---------------- transpose+pack the 6 GRU weight matrices (f32 -> bf16 pairs) ------
__global__ void k_transpose(const float* Wz, const float* Uz, const float* Wr, const float* Ur,
                            const float* Wh, const float* Uh, u32* Tp) {
    int bid = blockIdx.x;
    int m = bid >> 7, b = bid & 127;
    int idx = b * 256 + threadIdx.x;      // 0..32767
    int d2 = idx & 127, i = idx >> 7;     // coalesced f32 pair reads
    const float* src;
    switch (m) {
        case 0: src = Wz; break;
        case 1: src = Uz; break;
        case 2: src = Wr; break;
        case 3: src = Ur; break;
        case 4: src = Wh; break;
        default: src = Uh; break;
    }
    float lo = src[i * 256 + 2 * d2];
    float hi = src[i * 256 + 2 * d2 + 1];
    Tp[m * 32768 + d2 * 256 + i] = (u32)f2bf(lo) | ((u32)f2bf(hi) << 16);
}

// ---------------- scores: (x.p)/||p|| + mask, plus x -> bf16 conversion ----------------
__global__ __launch_bounds__(256) void k_scores(const float* x, const float* p, const float* mask,
                                                float* scores, u16* xb16) {
    __shared__ float pl[256];
    __shared__ float s_invn;
    int tid = threadIdx.x;
    pl[tid] = p[tid];
    __syncthreads();
    if (tid < 64) {
        float v = pl[tid] * pl[tid] + pl[tid + 64] * pl[tid + 64] +
                  pl[tid + 128] * pl[tid + 128] + pl[tid + 192] * pl[tid + 192];
        for (int o = 32; o > 0; o >>= 1) v += __shfl_xor(v, o);
        if (tid == 0) s_invn = 1.0f / sqrtf(v);
    }
    __syncthreads();
    int wid = tid >> 6, lane = tid & 63;
    for (int it = 0; it < 4; ++it) {
        int node = blockIdx.x * 16 + wid * 4 + it;   // 5000*16 == 80000
        const float* row = x + (size_t)node * DIN + lane * 4;
        float4 u = *(const float4*)row;
        float d = u.x * pl[lane * 4 + 0] + u.y * pl[lane * 4 + 1] +
                  u.z * pl[lane * 4 + 2] + u.w * pl[lane * 4 + 3];
        u32 p0 = (u32)f2bf(u.x) | ((u32)f2bf(u.y) << 16);
        u32 p1 = (u32)f2bf(u.z) | ((u32)f2bf(u.w) << 16);
        *(uint2*)(xb16 + (size_t)node * DIN + lane * 4) = make_uint2(p0, p1);
        for (int o = 32; o > 0; o >>= 1) d += __shfl_xor(d, o);
        if (lane == 0) scores[node] = d * s_invn + mask[node];
    }
}

// ---------------- phase 1: LDS-staged coarse binning (replaces k_count + k_place) ------
// Pack: bits [0,17) = t*N+src, [17,25) = dstLocal (0..159), [25,32) = bucket (0..124)
__global__ __launch_bounds__(256) void k_bin(const int* ei, const float* ew,
                                             int* gcur, uint2* binned) {
    int blk = blockIdx.x;                // 0..999
    int t = blk / 250, ci = blk - t * 250;
    int ebase = ci * 2560;
    int tid = threadIdx.x;
    __shared__ u32 hist[128], sc[128], gbase[128];
    __shared__ uint2 stage[2560];
    if (tid < 128) hist[tid] = 0;
    __syncthreads();
    u32 px[10]; u32 pw[10]; u16 rk[10];
#pragma unroll
    for (int k = 0; k < 10; ++k) {
        int e = ebase + tid + k * 256;                  // < E_ exactly
        int dst = ei[t * (2 * E_) + e];
        int src = ei[t * (2 * E_) + E_ + e];
        float w = ew[t * E_ + e];
        int b = dst / BNODES;                           // 0..124
        int dl = dst - b * BNODES;                      // 0..159
        px[k] = (u32)(t * N_ + src) | ((u32)dl << 17) | ((u32)b << 25);
        pw[k] = __float_as_uint(w);
        rk[k] = (u16)atomicAdd(&hist[b], 1u);
    }
    __syncthreads();
    // inclusive scan of hist (125 live, padded to 128)
    if (tid < 128) sc[tid] = hist[tid];
    __syncthreads();
    for (int o = 1; o < 128; o <<= 1) {
        u32 v = 0;
        if (tid < 128) { v = sc[tid]; if (tid >= o) v += sc[tid - o]; }
        __syncthreads();
        if (tid < 128) sc[tid] = v;
        __syncthreads();
    }
    // reserve contiguous global runs (one atomic per bucket per block)
    if (tid < NB) gbase[tid] = (u32)atomicAdd(&gcur[t * NB + tid], (int)hist[tid]);
    // stage into bucket-sorted LDS order: slot = exclusiveStart(b) + rank
#pragma unroll
    for (int k = 0; k < 10; ++k) {
        int b = px[k] >> 25;
        u32 slot = (sc[b] - hist[b]) + rk[k];
        stage[slot] = make_uint2(px[k], pw[k]);
    }
    __syncthreads();
    // flush: consecutive slots -> consecutive global addresses within each bucket run
    for (int s = tid; s < 2560; s += 256) {
        uint2 v = stage[s];
        int b = v.x >> 25;
        u32 local = gbase[b] + ((u32)s - (sc[b] - hist[b]));
        if (local < CAP)
            binned[(size_t)(t * NB + b) * CAP + local] = v;
    }
}

// ---------------- phase 2: in-place per-bucket sort by node + offsets + zero padding ---
__global__ __launch_bounds__(512) void k_scatter(const int* gcur, uint2* binned, int* offsets) {
    int bg = blockIdx.x;                 // 0..499
    int t = bg / NB, bl = bg - t * NB;
    uint2* bucket = binned + (size_t)bg * CAP;
    int cnt = gcur[bg]; if (cnt > CAP) cnt = CAP;
    int tid = threadIdx.x;
    __shared__ u32 nhist[256], sc2[256], nstart[BNODES];
    if (tid < 256) nhist[tid] = 0;
    __syncthreads();
    u32 vx[11]; u32 vw[11]; u16 r_[11];
#pragma unroll
    for (int k = 0; k < 11; ++k) {       // 11*512 = 5632 = CAP
        int e = tid + k * 512;
        r_[k] = 0xFFFFu;
        if (e < cnt) {
            uint2 v = bucket[e];
            vx[k] = v.x; vw[k] = v.y;
            int dl = (v.x >> 17) & 255;
            r_[k] = (u16)atomicAdd(&nhist[dl], 1u);
        }
    }
    __syncthreads();
    if (tid < 256) sc2[tid] = nhist[tid];
    __syncthreads();
    for (int o = 1; o < 256; o <<= 1) {
        u32 v = 0;
        if (tid < 256) { v = sc2[tid]; if (tid >= o) v += sc2[tid - o]; }
        __syncthreads();
        if (tid < 256) sc2[tid] = v;
        __syncthreads();
    }
    if (tid < BNODES) {
        u32 st = sc2[tid] - nhist[tid];
        nstart[tid] = st;
        offsets[t * N_ + bl * BNODES + tid] = bg * CAP + (int)st;
    }
    if (bg == NBTOT - 1 && tid == 0) offsets[NT] = NBTOT * CAP;
    __syncthreads();
#pragma unroll
    for (int k = 0; k < 11; ++k) {
        if (r_[k] != 0xFFFFu) {
            int dl = (vx[k] >> 17) & 255;
            u32 pos = nstart[dl] + r_[k];               // < cnt <= CAP
            bucket[pos] = make_uint2(vx[k] & 0x1FFFFu, vw[k]);
        }
    }
    // pad to capacity with zero-weight edges so offsets stay monotone through bucket ends
    for (int s = cnt + tid; s < CAP; s += 512) bucket[s] = make_uint2(0u, 0u);
}

// ---------------- top-128 (radix select, exact jax order) + xtT build ----------------
__global__ __launch_bounds__(1024) void k_topk(const float* scores, const float* x, float* xtT) {
    int t = blockIdx.x;
    int tid = threadIdx.x;   // 0..1023
    const float* sc = scores + t * N_;
    __shared__ u32 hist[256];
    __shared__ u32 sh_dig, sh_need;
    __shared__ u64 sel[256];
    __shared__ u32 selCount;
    __shared__ u32 idxl[128];
    __shared__ float tvl[128];

    u32 kreg[20];
#pragma unroll
    for (int p = 0; p < 20; ++p) {
        int i = tid + p * 1024;
        kreg[p] = (i < N_) ? fkey(sc[i]) : 0u;
    }

    u32 pref = 0;
    u32 need = 128;
    for (int pass = 0; pass < 4; ++pass) {
        int shift = 24 - 8 * pass;
        if (tid < 256) hist[tid] = 0;
        __syncthreads();
#pragma unroll
        for (int p = 0; p < 20; ++p) {
            int i = tid + p * 1024;
            u32 k = kreg[p];
            bool ok = (i < N_) && ((pass == 0) || ((k >> (shift + 8)) == pref));
            if (ok) atomicAdd(&hist[(k >> shift) & 255u], 1u);
        }
        __syncthreads();
        if (tid < 64) {
            int l = tid;
            u32 s = hist[4 * l] + hist[4 * l + 1] + hist[4 * l + 2] + hist[4 * l + 3];
            u32 S = s;
            for (int o = 1; o < 64; o <<= 1) {
                u32 y = __shfl_down(S, o);
                if (l + o < 64) S += y;
            }
            u64 m = __ballot(S >= need);
            int L = 63 - __builtin_clzll(m);
            if (l == L) {
                u32 Snext = S - s;
                u32 r = 0;
                for (int dd = 3; dd >= 0; --dd) {
                    u32 hb = hist[4 * L + dd];
                    r += hb;
                    if (Snext + r >= need) {
                        sh_dig = (u32)(4 * L + dd);
                        sh_need = need - (Snext + r - hb);
                        break;
                    }
                }
            }
        }
        __syncthreads();
        pref = (pref << 8) | sh_dig;
        need = sh_need;
        __syncthreads();
    }
    if (tid == 0) selCount = 0;
    __syncthreads();
    u32 theta = pref;
#pragma unroll
    for (int p = 0; p < 20; ++p) {
        int i = tid + p * 1024;
        u32 k = kreg[p];
        if (i < N_ && k >= theta) {
            u32 pos = atomicAdd(&selCount, 1u);
            if (pos < 256) sel[pos] = (((u64)(k ^ 0xFFFFFFFFu)) << 32) | (u32)i;
        }
    }
    __syncthreads();
    u32 c = selCount;
    if (c > 256) c = 256;
    if (tid < 256 && (u32)tid >= c) sel[tid] = 0xFFFFFFFFFFFFFFFFull;
    __syncthreads();
    // bitonic ascending sort: key = (~fkey)<<32 | idx  -> value desc, idx asc
    for (int k2 = 2; k2 <= 256; k2 <<= 1) {
        for (int jj = k2 >> 1; jj > 0; jj >>= 1) {
            if (tid < 256) {
                int i = tid, ixj = i ^ jj;
                if (ixj > i) {
                    u64 A = sel[i], B = sel[ixj];
                    bool asc = ((i & k2) == 0);
                    bool sw = asc ? (A > B) : (A < B);
                    if (sw) { sel[i] = B; sel[ixj] = A; }
                }
            }
            __syncthreads();
        }
    }
    if (tid < 128) {
        u64 v = sel[tid];
        u32 k = ((u32)(v >> 32)) ^ 0xFFFFFFFFu;
        idxl[tid] = (u32)(v & 0xFFFFFFFFu);
        tvl[tid] = tanhf(fkeyinv(k));
    }
    __syncthreads();
    float* xt_t = xtT + t * (DIN * DOUT);
    const float* xb = x + (size_t)t * N_ * DIN;
    for (int e2 = tid; e2 < DIN * DOUT; e2 += 1024) {
        int j = e2 >> 8, d = e2 & 255;
        xt_t[e2] = xb[(size_t)idxl[j] * DIN + d] * tvl[j];
    }
}

// ---------------- fused matrix-GRU: one block per 2 output columns (j0, j0+64) -------
__global__ __launch_bounds__(256) void k_gru(const float* xtT, const float* WprevT,
                                             const float* W0, int firstT, const u32* Tp,
                                             const float* bz, const float* br, const float* bh,
                                             float* WnextT, u16* WnT_t) {
    int j0 = blockIdx.x;          // 0..63
    int j1 = j0 + 64;
    int i = threadIdx.x;          // 0..255
    __shared__ float sxt[2][256], sW[2][256], srw[2][256];
    sxt[0][i] = xtT[j0 * 256 + i];
    sxt[1][i] = xtT[j1 * 256 + i];
    float wv0 = firstT ? W0[i * 128 + j0] : WprevT[j0 * 256 + i];
    float wv1 = firstT ? W0[i * 128 + j1] : WprevT[j1 * 256 + i];
    sW[0][i] = wv0;
    sW[1][i] = wv1;
    __syncthreads();
    const u32* WzT = Tp;
    const u32* UzT = Tp + 32768;
    const u32* WrT = Tp + 65536;
    const u32* UrT = Tp + 98304;
    const u32* WhT = Tp + 131072;
    const u32* UhT = Tp + 163840;
    float az0 = bz[i * 128 + j0], az1 = bz[i * 128 + j1];
    float ar0 = br[i * 128 + j0], ar1 = br[i * 128 + j1];
#pragma unroll 4
    for (int d2 = 0; d2 < 128; ++d2) {
        float x00 = sxt[0][2 * d2], x01 = sxt[0][2 * d2 + 1];
        float x10 = sxt[1][2 * d2], x11 = sxt[1][2 * d2 + 1];
        float w00 = sW[0][2 * d2], w01 = sW[0][2 * d2 + 1];
        float w10 = sW[1][2 * d2], w11 = sW[1][2 * d2 + 1];
        u32 a = WzT[d2 * 256 + i], b = UzT[d2 * 256 + i];
        u32 cc = WrT[d2 * 256 + i], dd = UrT[d2 * 256 + i];
        az0 += blo(a) * x00 + bhi(a) * x01 + blo(b) * w00 + bhi(b) * w01;
        az1 += blo(a) * x10 + bhi(a) * x11 + blo(b) * w10 + bhi(b) * w11;
        ar0 += blo(cc) * x00 + bhi(cc) * x01 + blo(dd) * w00 + bhi(dd) * w01;
        ar1 += blo(cc) * x10 + bhi(cc) * x11 + blo(dd) * w10 + bhi(dd) * w11;
    }
    float z0 = 1.0f / (1.0f + expf(-az0));
    float z1 = 1.0f / (1.0f + expf(-az1));
    float r0 = 1.0f / (1.0f + expf(-ar0));
    float r1 = 1.0f / (1.0f + expf(-ar1));
    srw[0][i] = r0 * wv0;
    srw[1][i] = r1 * wv1;
    __syncthreads();
    float ah0 = bh[i * 128 + j0], ah1 = bh[i * 128 + j1];
#pragma unroll 4
    for (int d2 = 0; d2 < 128; ++d2) {
        float x00 = sxt[0][2 * d2], x01 = sxt[0][2 * d2 + 1];
        float x10 = sxt[1][2 * d2], x11 = sxt[1][2 * d2 + 1];
        float r00 = srw[0][2 * d2], r01 = srw[0][2 * d2 + 1];
        float r10 = srw[1][2 * d2], r11 = srw[1][2 * d2 + 1];
        u32 a = WhT[d2 * 256 + i], b = UhT[d2 * 256 + i];
        ah0 += blo(a) * x00 + bhi(a) * x01 + blo(b) * r00 + bhi(b) * r01;
        ah1 += blo(a) * x10 + bhi(a) * x11 + blo(b) * r10 + bhi(b) * r11;
    }
    float h0 = tanhf(ah0), h1 = tanhf(ah1);
    float wn0 = (1.0f - z0) * wv0 + z0 * h0;
    float wn1 = (1.0f - z1) * wv1 + z1 * h1;
    WnextT[j0 * 256 + i] = wn0;
    WnextT[j1 * 256 + i] = wn1;
    WnT_t[j0 * 256 + i] = f2bf(wn0);
    WnT_t[j1 * 256 + i] = f2bf(wn1);
}

// ---------------- y = x_bf16 @ Wn (MFMA bf16), batched over t ----------------
__global__ __launch_bounds__(128) void k_gemm(const u16* xb16, const u16* WnT, u16* y) {
    int t = blockIdx.y;
    const u16* xb = xb16 + (size_t)t * N_ * DIN;
    const u16* Bt = WnT + t * (DIN * DOUT);
    u16* yb = y + (size_t)t * N_ * DOUT;
    int wid = threadIdx.x >> 6, lane = threadIdx.x & 63;
    int quad = lane >> 4, lm = lane & 15;
    int rowBase = blockIdx.x * 64 + wid * 32;
    f32x4 acc[2][8];
#pragma unroll
    for (int mi = 0; mi < 2; ++mi)
#pragma unroll
        for (int ni = 0; ni < 8; ++ni) acc[mi][ni] = (f32x4){0.f, 0.f, 0.f, 0.f};
    size_t aoff[2];
#pragma unroll
    for (int mi = 0; mi < 2; ++mi) {
        int r = rowBase + mi * 16 + lm;
        if (r > N_ - 1) r = N_ - 1;
        aoff[mi] = (size_t)r * DIN + quad * 8;
    }
    const u16* bbase = Bt + lm * 256 + quad * 8;
    for (int kk = 0; kk < 256; kk += 32) {
        short8 a0 = *(const short8*)(xb + aoff[0] + kk);
        short8 a1 = *(const short8*)(xb + aoff[1] + kk);
#pragma unroll
        for (int ni = 0; ni < 8; ++ni) {
            short8 b = *(const short8*)(bbase + ni * 4096 + kk);
            acc[0][ni] = __builtin_amdgcn_mfma_f32_16x16x32_bf16(a0, b, acc[0][ni], 0, 0, 0);
            acc[1][ni] = __builtin_amdgcn_mfma_f32_16x16x32_bf16(a1, b, acc[1][ni], 0, 0, 0);
        }
    }
#pragma unroll
    for (int mi = 0; mi < 2; ++mi)
#pragma unroll
        for (int ni = 0; ni < 8; ++ni)
#pragma unroll
            for (int r = 0; r < 4; ++r) {
                int row = rowBase + mi * 16 + quad * 4 + r;
                if (row < N_) yb[(size_t)row * DOUT + ni * 16 + lm] = f2bf(acc[mi][ni][r]);
            }
}

// ---------------- CSR gather-aggregate: 8 edges in flight per wave ----------------
// XCD-aware swizzle: 20000 blocks, 8 XCDs, round-robin dispatch assumed.
// newbid = (bid%8)*2500 + bid/8 gives XCD k the contiguous node range
// [k*10000, (k+1)*10000) -- all within ONE timestep (t = k/2), so the random
// y-row gather footprint per XCD-L2 is y_t = 5.12 MB instead of all-t 20.5 MB.
__global__ __launch_bounds__(256) void k_agg(const int* offsets, const uint2* srcw,
                                             const u16* y, float* out) {
    int nb = (blockIdx.x & 7) * 2500 + (blockIdx.x >> 3);   // bijective: 20000 % 8 == 0
    int g = nb * 4 + (threadIdx.x >> 6);   // < NT
    int lane = threadIdx.x & 63;
    int q = lane >> 4, lq = lane & 15;
    int o0 = offsets[g], o1 = offsets[g + 1];
    float acc[8];
#pragma unroll
    for (int i = 0; i < 8; ++i) acc[i] = 0.f;
    int e0 = o0;
    for (; e0 + 8 <= o1; e0 += 8) {
        int ea = e0 + q, eb = e0 + 4 + q;
        uint2 ma = srcw[ea];
        uint2 mb = srcw[eb];
        float wa = __uint_as_float(ma.y);
        float wb = __uint_as_float(mb.y);
        uint4 va = *(const uint4*)(y + (size_t)ma.x * DOUT + lq * 8);
        uint4 vb = *(const uint4*)(y + (size_t)mb.x * DOUT + lq * 8);
        acc[0] += wa * blo(va.x); acc[1] += wa * bhi(va.x);
        acc[2] += wa * blo(va.y); acc[3] += wa * bhi(va.y);
        acc[4] += wa * blo(va.z); acc[5] += wa * bhi(va.z);
        acc[6] += wa * blo(va.w); acc[7] += wa * bhi(va.w);
        acc[0] += wb * blo(vb.x); acc[1] += wb * bhi(vb.x);
        acc[2] += wb * blo(vb.y); acc[3] += wb * bhi(vb.y);
        acc[4] += wb * blo(vb.z); acc[5] += wb * bhi(vb.z);
        acc[6] += wb * blo(vb.w); acc[7] += wb * bhi(vb.w);
    }
    for (; e0 < o1; e0 += 4) {
        int e = e0 + q;
        if (e < o1) {
            uint2 m = srcw[e];
            float wv = __uint_as_float(m.y);
            uint4 v = *(const uint4*)(y + (size_t)m.x * DOUT + lq * 8);
            acc[0] += wv * blo(v.x); acc[1] += wv * bhi(v.x);
            acc[2] += wv * blo(v.y); acc[3] += wv * bhi(v.y);
            acc[4] += wv * blo(v.z); acc[5] += wv * bhi(v.z);
            acc[6] += wv * blo(v.w); acc[7] += wv * bhi(v.w);
        }
    }
#pragma unroll
    for (int i = 0; i < 8; ++i) {
        acc[i] += __shfl_xor(acc[i], 16);
        acc[i] += __shfl_xor(acc[i], 32);
        acc[i] = (acc[i] >= 0.f) ? acc[i] : SLOPE * acc[i];
    }
    if (q == 0) {
        float4 v0 = make_float4(acc[0], acc[1], acc[2], acc[3]);
        float4 v1 = make_float4(acc[4], acc[5], acc[6], acc[7]);
        float* ob = out + (size_t)g * DOUT + lq * 8;
        *(float4*)ob = v0;
        *(float4*)(ob + 4) = v1;
    }
}

extern "C" void kernel_launch(void* const* d_in, const int* in_sizes, int n_in,
                              void* d_out, int out_size, void* d_ws, size_t ws_size,
                              hipStream_t stream) {
    const float* x = (const float*)d_in[0];
    const int* ei = (const int*)d_in[1];
    const float* ew = (const float*)d_in[2];
    const float* mask = (const float*)d_in[3];
    const float* p = (const float*)d_in[4];
    const float* Wz = (const float*)d_in[5];
    const float* Uz = (const float*)d_in[6];
    const float* bz = (const float*)d_in[7];
    const float* Wr = (const float*)d_in[8];
    const float* Ur = (const float*)d_in[9];
    const float* br = (const float*)d_in[10];
    const float* Wh = (const float*)d_in[11];
    const float* Uh = (const float*)d_in[12];
    const float* bh = (const float*)d_in[13];
    const float* W0 = (const float*)d_in[14];
    float* out = (float*)d_out;

    char* w = (char*)d_ws;
    u16* xb16 = (u16*)w;        w += (size_t)NT * DIN * 2;        // 40,960,000
    float* scores = (float*)w;  w += 320256;                      // NT f32
    float* xtT = (float*)w;     w += 4 * 32768 * 4;               // [t][128][256] f32
    float* Wst = (float*)w;     w += 2 * 32768 * 4;               // ping-pong W^T state f32
    u16* WnT = (u16*)w;         w += 4 * 32768 * 2;               // [t][128][256] bf16
    u32* Tp = (u32*)w;          w += 6 * 32768 * 4;               // packed transposed weights
    u16* y = (u16*)w;           w += (size_t)NT * DOUT * 2;       // [t][N][128] bf16
    uint2* binned = (uint2*)w;  w += (size_t)NBTOT * CAP * 8;     // bucketed edges -> final CSR (in place)
    int* gcur = (int*)w;        w += 2048;                        // 500 bucket cursors
    int* offsets = (int*)w;     w += 320256;                      // NT+1

    hipMemsetAsync(gcur, 0, 2048, stream);

    k_transpose<<<768, 256, 0, stream>>>(Wz, Uz, Wr, Ur, Wh, Uh, Tp);
    k_scores<<<5000, 256, 0, stream>>>(x, p, mask, scores, xb16);
    k_bin<<<1000, 256, 0, stream>>>(ei, ew, gcur, binned);
    k_scatter<<<NBTOT, 512, 0, stream>>>(gcur, binned, offsets);
    k_topk<<<4, 1024, 0, stream>>>(scores, x, xtT);

    for (int t = 0; t < 4; ++t) {
        const float* WprevT = (t == 0) ? Wst : (Wst + ((t + 1) & 1) * 32768);
        float* WnextT = Wst + (t & 1) * 32768;
        k_gru<<<64, 256, 0, stream>>>(xtT + t * 32768, WprevT, W0, (t == 0) ? 1 : 0, Tp,
                                      bz, br, bh, WnextT, WnT + t * 32768);
    }
    k_gemm<<<dim3(313, 4), 128, 0, stream>>>(xb16, WnT, y);
    k_agg<<<N_, 256, 0, stream>>>(offsets, binned, y, out);
}

// Round 3
// 462.118 us; speedup vs baseline: 1.3944x; 1.0220x over previous
//
#include <hip/hip_runtime.h>

typedef unsigned short u16;
typedef unsigned int u32;
typedef unsigned long long u64;

#define T_ 4
#define N_ 20000
#define E_ 640000
#define DIN 256
#define DOUT 128
#define NT (T_*N_)          // 80000
#define TE (T_*E_)          // 2560000
#define SLOPE 0.22916666666666666f

// coarse binning geometry: 125 buckets of 160 nodes per timestep
#define NB 125
#define BNODES 160
#define CAP 5632            // mean 5120, sigma ~72 -> 14 sigma headroom
#define NBTOT (T_*NB)       // 500

// k_scatter composite sort: secondary key = src block of 2048 nodes
#define SGRAN 11
#define NSB 10              // ceil(20000 / 2048)
#define NBIN (BNODES*NSB)   // 1600
#define NBIN_PAD 2048

typedef __attribute__((ext_vector_type(8))) short short8;
typedef __attribute__((ext_vector_type(4))) float f32x4;

__device__ __forceinline__ float blo(u32 u) { return __uint_as_float(u << 16); }
__device__ __forceinline__ float bhi(u32 u) { return __uint_as_float(u & 0xFFFF0000u); }
__device__ __forceinline__ u16 f2bf(float f) {
    u32 u = __float_as_uint(f);
    return (u16)((u + 0x7FFFu + ((u >> 16) & 1u)) >> 16);
}
__device__ __forceinline__ u32 fkey(float f) {
    u32 u = __float_as_uint(f);
    return (u & 0x80000000u) ? ~u : (u | 0x80000000u);
}
__device__ __forceinline__ float fkeyinv(u32 k) {
    u32 u = (k & 0x80000000u) ? (k ^ 0x80000000u) : ~k;
    return __uint_as_float(u);
}

// ---------------- transpose+pack the 6 GRU weight matrices (f32 -> bf16 pairs) ------
__global__ void k_transpose(const float* Wz, const float* Uz, const float* Wr, const float* Ur,
                            const float* Wh, const float* Uh, u32* Tp) {
    int bid = blockIdx.x;
    int m = bid >> 7, b = bid & 127;
    int idx = b * 256 + threadIdx.x;      // 0..32767
    int d2 = idx & 127, i = idx >> 7;     // coalesced f32 pair reads
    const float* src;
    switch (m) {
        case 0: src = Wz; break;
        case 1: src = Uz; break;
        case 2: src = Wr; break;
        case 3: src = Ur; break;
        case 4: src = Wh; break;
        default: src = Uh; break;
    }
    float lo = src[i * 256 + 2 * d2];
    float hi = src[i * 256 + 2 * d2 + 1];
    Tp[m * 32768 + d2 * 256 + i] = (u32)f2bf(lo) | ((u32)f2bf(hi) << 16);
}

// ---------------- scores: (x.p)/||p|| + mask, plus x -> bf16 conversion ----------------
__global__ __launch_bounds__(256) void k_scores(const float* x, const float* p, const float* mask,
                                                float* scores, u16* xb16) {
    __shared__ float pl[256];
    __shared__ float s_invn;
    int tid = threadIdx.x;
    pl[tid] = p[tid];
    __syncthreads();
    if (tid < 64) {
        float v = pl[tid] * pl[tid] + pl[tid + 64] * pl[tid + 64] +
                  pl[tid + 128] * pl[tid + 128] + pl[tid + 192] * pl[tid + 192];
        for (int o = 32; o > 0; o >>= 1) v += __shfl_xor(v, o);
        if (tid == 0) s_invn = 1.0f / sqrtf(v);
    }
    __syncthreads();
    int wid = tid >> 6, lane = tid & 63;
    for (int it = 0; it < 4; ++it) {
        int node = blockIdx.x * 16 + wid * 4 + it;   // 5000*16 == 80000
        const float* row = x + (size_t)node * DIN + lane * 4;
        float4 u = *(const float4*)row;
        float d = u.x * pl[lane * 4 + 0] + u.y * pl[lane * 4 + 1] +
                  u.z * pl[lane * 4 + 2] + u.w * pl[lane * 4 + 3];
        u32 p0 = (u32)f2bf(u.x) | ((u32)f2bf(u.y) << 16);
        u32 p1 = (u32)f2bf(u.z) | ((u32)f2bf(u.w) << 16);
        *(uint2*)(xb16 + (size_t)node * DIN + lane * 4) = make_uint2(p0, p1);
        for (int o = 32; o > 0; o >>= 1) d += __shfl_xor(d, o);
        if (lane == 0) scores[node] = d * s_invn + mask[node];
    }
}

// ---------------- phase 1: LDS-staged coarse binning (replaces k_count + k_place) ------
// Pack: bits [0,17) = t*N+src, [17,25) = dstLocal (0..159), [25,32) = bucket (0..124)
__global__ __launch_bounds__(256) void k_bin(const int* ei, const float* ew,
                                             int* gcur, uint2* binned) {
    int blk = blockIdx.x;                // 0..999
    int t = blk / 250, ci = blk - t * 250;
    int ebase = ci * 2560;
    int tid = threadIdx.x;
    __shared__ u32 hist[128], sc[128], gbase[128];
    __shared__ uint2 stage[2560];
    if (tid < 128) hist[tid] = 0;
    __syncthreads();
    u32 px[10]; u32 pw[10]; u16 rk[10];
#pragma unroll
    for (int k = 0; k < 10; ++k) {
        int e = ebase + tid + k * 256;                  // < E_ exactly
        int dst = ei[t * (2 * E_) + e];
        int src = ei[t * (2 * E_) + E_ + e];
        float w = ew[t * E_ + e];
        int b = dst / BNODES;                           // 0..124
        int dl = dst - b * BNODES;                      // 0..159
        px[k] = (u32)(t * N_ + src) | ((u32)dl << 17) | ((u32)b << 25);
        pw[k] = __float_as_uint(w);
        rk[k] = (u16)atomicAdd(&hist[b], 1u);
    }
    __syncthreads();
    // inclusive scan of hist (125 live, padded to 128)
    if (tid < 128) sc[tid] = hist[tid];
    __syncthreads();
    for (int o = 1; o < 128; o <<= 1) {
        u32 v = 0;
        if (tid < 128) { v = sc[tid]; if (tid >= o) v += sc[tid - o]; }
        __syncthreads();
        if (tid < 128) sc[tid] = v;
        __syncthreads();
    }
    // reserve contiguous global runs (one atomic per bucket per block)
    if (tid < NB) gbase[tid] = (u32)atomicAdd(&gcur[t * NB + tid], (int)hist[tid]);
    // stage into bucket-sorted LDS order: slot = exclusiveStart(b) + rank
#pragma unroll
    for (int k = 0; k < 10; ++k) {
        int b = px[k] >> 25;
        u32 slot = (sc[b] - hist[b]) + rk[k];
        stage[slot] = make_uint2(px[k], pw[k]);
    }
    __syncthreads();
    // flush: consecutive slots -> consecutive global addresses within each bucket run
    for (int s = tid; s < 2560; s += 256) {
        uint2 v = stage[s];
        int b = v.x >> 25;
        u32 local = gbase[b] + ((u32)s - (sc[b] - hist[b]));
        if (local < CAP)
            binned[(size_t)(t * NB + b) * CAP + local] = v;
    }
}

// ---------------- phase 2: in-place per-bucket counting sort by (node, src>>11) --------
// src-sorted within-node edge order: concurrently-active waves across an XCD then
// reference the same src quantile band -> y-gather working set fits in 4MB L2.
__global__ __launch_bounds__(512) void k_scatter(const int* gcur, uint2* binned, int* offsets) {
    int bg = blockIdx.x;                 // 0..499
    int t = bg / NB, bl = bg - t * NB;
    uint2* bucket = binned + (size_t)bg * CAP;
    int cnt = gcur[bg]; if (cnt > CAP) cnt = CAP;
    int tid = threadIdx.x;
    int tbase = t * N_;
    __shared__ u32 nhist[NBIN_PAD];
    __shared__ u32 binstart[NBIN_PAD];
    __shared__ u32 wsum[8];
    for (int i = tid; i < NBIN_PAD; i += 512) nhist[i] = 0;
    __syncthreads();
    u32 vx[11]; u32 vw[11]; u16 r_[11]; u16 bn_[11];
#pragma unroll
    for (int k = 0; k < 11; ++k) {       // 11*512 = 5632 = CAP
        int e = tid + k * 512;
        r_[k] = 0xFFFFu;
        if (e < cnt) {
            uint2 v = bucket[e];
            vx[k] = v.x; vw[k] = v.y;
            int dl = (v.x >> 17) & 255;
            int s = (int)(v.x & 0x1FFFFu) - tbase;      // 0..19999
            int bin = dl * NSB + (s >> SGRAN);          // 0..1599
            bn_[k] = (u16)bin;
            r_[k] = (u16)atomicAdd(&nhist[bin], 1u);
        }
    }
    __syncthreads();
    // exclusive scan over 2048 bins: thread sums 4, then scan 512 thread-sums
    u32 loc1, loc2, loc3, tsum;
    {
        int b0 = tid * 4;
        u32 a = nhist[b0], b = nhist[b0 + 1], c = nhist[b0 + 2], d = nhist[b0 + 3];
        loc1 = a; loc2 = a + b; loc3 = a + b + c; tsum = a + b + c + d;
    }
    int lane = tid & 63, wv = tid >> 6;
    u32 xsc = tsum;
    for (int o = 1; o < 64; o <<= 1) { u32 yv = __shfl_up(xsc, o); if (lane >= o) xsc += yv; }
    if (lane == 63) wsum[wv] = xsc;
    __syncthreads();
    u32 wpre = 0;
    for (int wq = 0; wq < wv; ++wq) wpre += wsum[wq];
    u32 tpre = wpre + xsc - tsum;
    {
        int b0 = tid * 4;
        binstart[b0] = tpre;
        binstart[b0 + 1] = tpre + loc1;
        binstart[b0 + 2] = tpre + loc2;
        binstart[b0 + 3] = tpre + loc3;
    }
    __syncthreads();
    if (tid < BNODES)
        offsets[t * N_ + bl * BNODES + tid] = bg * CAP + (int)binstart[tid * NSB];
    if (bg == NBTOT - 1 && tid == 0) offsets[NT] = NBTOT * CAP;
#pragma unroll
    for (int k = 0; k < 11; ++k) {
        if (r_[k] != 0xFFFFu) {
            u32 pos = binstart[bn_[k]] + r_[k];         // < cnt <= CAP
            bucket[pos] = make_uint2(vx[k] & 0x1FFFFu, vw[k]);
        }
    }
    // pad to capacity with zero-weight edges so offsets stay monotone through bucket ends
    for (int s2 = cnt + tid; s2 < CAP; s2 += 512) bucket[s2] = make_uint2(0u, 0u);
}

// ---------------- top-128 (radix select, exact jax order) + xtT build ----------------
__global__ __launch_bounds__(1024) void k_topk(const float* scores, const float* x, float* xtT) {
    int t = blockIdx.x;
    int tid = threadIdx.x;   // 0..1023
    const float* sc = scores + t * N_;
    __shared__ u32 hist[256];
    __shared__ u32 sh_dig, sh_need;
    __shared__ u64 sel[256];
    __shared__ u32 selCount;
    __shared__ u32 idxl[128];
    __shared__ float tvl[128];

    u32 kreg[20];
#pragma unroll
    for (int p = 0; p < 20; ++p) {
        int i = tid + p * 1024;
        kreg[p] = (i < N_) ? fkey(sc[i]) : 0u;
    }

    u32 pref = 0;
    u32 need = 128;
    for (int pass = 0; pass < 4; ++pass) {
        int shift = 24 - 8 * pass;
        if (tid < 256) hist[tid] = 0;
        __syncthreads();
#pragma unroll
        for (int p = 0; p < 20; ++p) {
            int i = tid + p * 1024;
            u32 k = kreg[p];
            bool ok = (i < N_) && ((pass == 0) || ((k >> (shift + 8)) == pref));
            if (ok) atomicAdd(&hist[(k >> shift) & 255u], 1u);
        }
        __syncthreads();
        if (tid < 64) {
            int l = tid;
            u32 s = hist[4 * l] + hist[4 * l + 1] + hist[4 * l + 2] + hist[4 * l + 3];
            u32 S = s;
            for (int o = 1; o < 64; o <<= 1) {
                u32 y = __shfl_down(S, o);
                if (l + o < 64) S += y;
            }
            u64 m = __ballot(S >= need);
            int L = 63 - __builtin_clzll(m);
            if (l == L) {
                u32 Snext = S - s;
                u32 r = 0;
                for (int dd = 3; dd >= 0; --dd) {
                    u32 hb = hist[4 * L + dd];
                    r += hb;
                    if (Snext + r >= need) {
                        sh_dig = (u32)(4 * L + dd);
                        sh_need = need - (Snext + r - hb);
                        break;
                    }
                }
            }
        }
        __syncthreads();
        pref = (pref << 8) | sh_dig;
        need = sh_need;
        __syncthreads();
    }
    if (tid == 0) selCount = 0;
    __syncthreads();
    u32 theta = pref;
#pragma unroll
    for (int p = 0; p < 20; ++p) {
        int i = tid + p * 1024;
        u32 k = kreg[p];
        if (i < N_ && k >= theta) {
            u32 pos = atomicAdd(&selCount, 1u);
            if (pos < 256) sel[pos] = (((u64)(k ^ 0xFFFFFFFFu)) << 32) | (u32)i;
        }
    }
    __syncthreads();
    u32 c = selCount;
    if (c > 256) c = 256;
    if (tid < 256 && (u32)tid >= c) sel[tid] = 0xFFFFFFFFFFFFFFFFull;
    __syncthreads();
    // bitonic ascending sort: key = (~fkey)<<32 | idx  -> value desc, idx asc
    for (int k2 = 2; k2 <= 256; k2 <<= 1) {
        for (int jj = k2 >> 1; jj > 0; jj >>= 1) {
            if (tid < 256) {
                int i = tid, ixj = i ^ jj;
                if (ixj > i) {
                    u64 A = sel[i], B = sel[ixj];
                    bool asc = ((i & k2) == 0);
                    bool sw = asc ? (A > B) : (A < B);
                    if (sw) { sel[i] = B; sel[ixj] = A; }
                }
            }
            __syncthreads();
        }
    }
    if (tid < 128) {
        u64 v = sel[tid];
        u32 k = ((u32)(v >> 32)) ^ 0xFFFFFFFFu;
        idxl[tid] = (u32)(v & 0xFFFFFFFFu);
        tvl[tid] = tanhf(fkeyinv(k));
    }
    __syncthreads();
    float* xt_t = xtT + t * (DIN * DOUT);
    const float* xb = x + (size_t)t * N_ * DIN;
    for (int e2 = tid; e2 < DIN * DOUT; e2 += 1024) {
        int j = e2 >> 8, d = e2 & 255;
        xt_t[e2] = xb[(size_t)idxl[j] * DIN + d] * tvl[j];
    }
}

// ---------------- fused matrix-GRU: one block per 2 output columns (j0, j0+64) -------
__global__ __launch_bounds__(256) void k_gru(const float* xtT, const float* WprevT,
                                             const float* W0, int firstT, const u32* Tp,
                                             const float* bz, const float* br, const float* bh,
                                             float* WnextT, u16* WnT_t) {
    int j0 = blockIdx.x;          // 0..63
    int j1 = j0 + 64;
    int i = threadIdx.x;          // 0..255
    __shared__ float sxt[2][256], sW[2][256], srw[2][256];
    sxt[0][i] = xtT[j0 * 256 + i];
    sxt[1][i] = xtT[j1 * 256 + i];
    float wv0 = firstT ? W0[i * 128 + j0] : WprevT[j0 * 256 + i];
    float wv1 = firstT ? W0[i * 128 + j1] : WprevT[j1 * 256 + i];
    sW[0][i] = wv0;
    sW[1][i] = wv1;
    __syncthreads();
    const u32* WzT = Tp;
    const u32* UzT = Tp + 32768;
    const u32* WrT = Tp + 65536;
    const u32* UrT = Tp + 98304;
    const u32* WhT = Tp + 131072;
    const u32* UhT = Tp + 163840;
    float az0 = bz[i * 128 + j0], az1 = bz[i * 128 + j1];
    float ar0 = br[i * 128 + j0], ar1 = br[i * 128 + j1];
#pragma unroll 4
    for (int d2 = 0; d2 < 128; ++d2) {
        float x00 = sxt[0][2 * d2], x01 = sxt[0][2 * d2 + 1];
        float x10 = sxt[1][2 * d2], x11 = sxt[1][2 * d2 + 1];
        float w00 = sW[0][2 * d2], w01 = sW[0][2 * d2 + 1];
        float w10 = sW[1][2 * d2], w11 = sW[1][2 * d2 + 1];
        u32 a = WzT[d2 * 256 + i], b = UzT[d2 * 256 + i];
        u32 cc = WrT[d2 * 256 + i], dd = UrT[d2 * 256 + i];
        az0 += blo(a) * x00 + bhi(a) * x01 + blo(b) * w00 + bhi(b) * w01;
        az1 += blo(a) * x10 + bhi(a) * x11 + blo(b) * w10 + bhi(b) * w11;
        ar0 += blo(cc) * x00 + bhi(cc) * x01 + blo(dd) * w00 + bhi(dd) * w01;
        ar1 += blo(cc) * x10 + bhi(cc) * x11 + blo(dd) * w10 + bhi(dd) * w11;
    }
    float z0 = 1.0f / (1.0f + expf(-az0));
    float z1 = 1.0f / (1.0f + expf(-az1));
    float r0 = 1.0f / (1.0f + expf(-ar0));
    float r1 = 1.0f / (1.0f + expf(-ar1));
    srw[0][i] = r0 * wv0;
    srw[1][i] = r1 * wv1;
    __syncthreads();
    float ah0 = bh[i * 128 + j0], ah1 = bh[i * 128 + j1];
#pragma unroll 4
    for (int d2 = 0; d2 < 128; ++d2) {
        float x00 = sxt[0][2 * d2], x01 = sxt[0][2 * d2 + 1];
        float x10 = sxt[1][2 * d2], x11 = sxt[1][2 * d2 + 1];
        float r00 = srw[0][2 * d2], r01 = srw[0][2 * d2 + 1];
        float r10 = srw[1][2 * d2], r11 = srw[1][2 * d2 + 1];
        u32 a = WhT[d2 * 256 + i], b = UhT[d2 * 256 + i];
        ah0 += blo(a) * x00 + bhi(a) * x01 + blo(b) * r00 + bhi(b) * r01;
        ah1 += blo(a) * x10 + bhi(a) * x11 + blo(b) * r10 + bhi(b) * r11;
    }
    float h0 = tanhf(ah0), h1 = tanhf(ah1);
    float wn0 = (1.0f - z0) * wv0 + z0 * h0;
    float wn1 = (1.0f - z1) * wv1 + z1 * h1;
    WnextT[j0 * 256 + i] = wn0;
    WnextT[j1 * 256 + i] = wn1;
    WnT_t[j0 * 256 + i] = f2bf(wn0);
    WnT_t[j1 * 256 + i] = f2bf(wn1);
}

// ---------------- y = x_bf16 @ Wn (MFMA bf16), batched over t ----------------
__global__ __launch_bounds__(128) void k_gemm(const u16* xb16, const u16* WnT, u16* y) {
    int t = blockIdx.y;
    const u16* xb = xb16 + (size_t)t * N_ * DIN;
    const u16* Bt = WnT + t * (DIN * DOUT);
    u16* yb = y + (size_t)t * N_ * DOUT;
    int wid = threadIdx.x >> 6, lane = threadIdx.x & 63;
    int quad = lane >> 4, lm = lane & 15;
    int rowBase = blockIdx.x * 64 + wid * 32;
    f32x4 acc[2][8];
#pragma unroll
    for (int mi = 0; mi < 2; ++mi)
#pragma unroll
        for (int ni = 0; ni < 8; ++ni) acc[mi][ni] = (f32x4){0.f, 0.f, 0.f, 0.f};
    size_t aoff[2];
#pragma unroll
    for (int mi = 0; mi < 2; ++mi) {
        int r = rowBase + mi * 16 + lm;
        if (r > N_ - 1) r = N_ - 1;
        aoff[mi] = (size_t)r * DIN + quad * 8;
    }
    const u16* bbase = Bt + lm * 256 + quad * 8;
    for (int kk = 0; kk < 256; kk += 32) {
        short8 a0 = *(const short8*)(xb + aoff[0] + kk);
        short8 a1 = *(const short8*)(xb + aoff[1] + kk);
#pragma unroll
        for (int ni = 0; ni < 8; ++ni) {
            short8 b = *(const short8*)(bbase + ni * 4096 + kk);
            acc[0][ni] = __builtin_amdgcn_mfma_f32_16x16x32_bf16(a0, b, acc[0][ni], 0, 0, 0);
            acc[1][ni] = __builtin_amdgcn_mfma_f32_16x16x32_bf16(a1, b, acc[1][ni], 0, 0, 0);
        }
    }
#pragma unroll
    for (int mi = 0; mi < 2; ++mi)
#pragma unroll
        for (int ni = 0; ni < 8; ++ni)
#pragma unroll
            for (int r = 0; r < 4; ++r) {
                int row = rowBase + mi * 16 + quad * 4 + r;
                if (row < N_) yb[(size_t)row * DOUT + ni * 16 + lm] = f2bf(acc[mi][ni][r]);
            }
}

// ---------------- CSR gather-aggregate: 16 edges in flight per wave ----------------
// XCD-aware swizzle: newbid = (bid%8)*2500 + bid/8 (bijective, 20000 % 8 == 0).
#define ACC8(wv, v)                                             \
    acc[0] += wv * blo(v.x); acc[1] += wv * bhi(v.x);           \
    acc[2] += wv * blo(v.y); acc[3] += wv * bhi(v.y);           \
    acc[4] += wv * blo(v.z); acc[5] += wv * bhi(v.z);           \
    acc[6] += wv * blo(v.w); acc[7] += wv * bhi(v.w);

__global__ __launch_bounds__(256) void k_agg(const int* offsets, const uint2* srcw,
                                             const u16* y, float* out) {
    int nb = (blockIdx.x & 7) * 2500 + (blockIdx.x >> 3);
    int g = nb * 4 + (threadIdx.x >> 6);   // < NT
    int lane = threadIdx.x & 63;
    int q = lane >> 4, lq = lane & 15;
    int o0 = offsets[g], o1 = offsets[g + 1];
    float acc[8];
#pragma unroll
    for (int i = 0; i < 8; ++i) acc[i] = 0.f;
    int e0 = o0;
    for (; e0 + 16 <= o1; e0 += 16) {
        uint2 m0 = srcw[e0 + q];
        uint2 m1 = srcw[e0 + 4 + q];
        uint2 m2 = srcw[e0 + 8 + q];
        uint2 m3 = srcw[e0 + 12 + q];
        uint4 v0 = *(const uint4*)(y + (size_t)m0.x * DOUT + lq * 8);
        uint4 v1 = *(const uint4*)(y + (size_t)m1.x * DOUT + lq * 8);
        uint4 v2 = *(const uint4*)(y + (size_t)m2.x * DOUT + lq * 8);
        uint4 v3 = *(const uint4*)(y + (size_t)m3.x * DOUT + lq * 8);
        float w0 = __uint_as_float(m0.y);
        float w1 = __uint_as_float(m1.y);
        float w2 = __uint_as_float(m2.y);
        float w3 = __uint_as_float(m3.y);
        ACC8(w0, v0)
        ACC8(w1, v1)
        ACC8(w2, v2)
        ACC8(w3, v3)
    }
    for (; e0 + 8 <= o1; e0 += 8) {
        uint2 ma = srcw[e0 + q];
        uint2 mb = srcw[e0 + 4 + q];
        uint4 va = *(const uint4*)(y + (size_t)ma.x * DOUT + lq * 8);
        uint4 vb = *(const uint4*)(y + (size_t)mb.x * DOUT + lq * 8);
        float wa = __uint_as_float(ma.y);
        float wb = __uint_as_float(mb.y);
        ACC8(wa, va)
        ACC8(wb, vb)
    }
    for (; e0 < o1; e0 += 4) {
        int e = e0 + q;
        if (e < o1) {
            uint2 m = srcw[e];
            float wv = __uint_as_float(m.y);
            uint4 v = *(const uint4*)(y + (size_t)m.x * DOUT + lq * 8);
            ACC8(wv, v)
        }
    }
#pragma unroll
    for (int i = 0; i < 8; ++i) {
        acc[i] += __shfl_xor(acc[i], 16);
        acc[i] += __shfl_xor(acc[i], 32);
        acc[i] = (acc[i] >= 0.f) ? acc[i] : SLOPE * acc[i];
    }
    if (q == 0) {
        float4 v0 = make_float4(acc[0], acc[1], acc[2], acc[3]);
        float4 v1 = make_float4(acc[4], acc[5], acc[6], acc[7]);
        float* ob = out + (size_t)g * DOUT + lq * 8;
        *(float4*)ob = v0;
        *(float4*)(ob + 4) = v1;
    }
}

extern "C" void kernel_launch(void* const* d_in, const int* in_sizes, int n_in,
                              void* d_out, int out_size, void* d_ws, size_t ws_size,
                              hipStream_t stream) {
    const float* x = (const float*)d_in[0];
    const int* ei = (const int*)d_in[1];
    const float* ew = (const float*)d_in[2];
    const float* mask = (const float*)d_in[3];
    const float* p = (const float*)d_in[4];
    const float* Wz = (const float*)d_in[5];
    const float* Uz = (const float*)d_in[6];
    const float* bz = (const float*)d_in[7];
    const float* Wr = (const float*)d_in[8];
    const float* Ur = (const float*)d_in[9];
    const float* br = (const float*)d_in[10];
    const float* Wh = (const float*)d_in[11];
    const float* Uh = (const float*)d_in[12];
    const float* bh = (const float*)d_in[13];
    const float* W0 = (const float*)d_in[14];
    float* out = (float*)d_out;

    char* w = (char*)d_ws;
    u16* xb16 = (u16*)w;        w += (size_t)NT * DIN * 2;        // 40,960,000
    float* scores = (float*)w;  w += 320256;                      // NT f32
    float* xtT = (float*)w;     w += 4 * 32768 * 4;               // [t][128][256] f32
    float* Wst = (float*)w;     w += 2 * 32768 * 4;               // ping-pong W^T state f32
    u16* WnT = (u16*)w;         w += 4 * 32768 * 2;               // [t][128][256] bf16
    u32* Tp = (u32*)w;          w += 6 * 32768 * 4;               // packed transposed weights
    u16* y = (u16*)w;           w += (size_t)NT * DOUT * 2;       // [t][N][128] bf16
    uint2* binned = (uint2*)w;  w += (size_t)NBTOT * CAP * 8;     // bucketed edges -> final CSR (in place)
    int* gcur = (int*)w;        w += 2048;                        // 500 bucket cursors
    int* offsets = (int*)w;     w += 320256;                      // NT+1

    hipMemsetAsync(gcur, 0, 2048, stream);

    k_transpose<<<768, 256, 0, stream>>>(Wz, Uz, Wr, Ur, Wh, Uh, Tp);
    k_scores<<<5000, 256, 0, stream>>>(x, p, mask, scores, xb16);
    k_bin<<<1000, 256, 0, stream>>>(ei, ew, gcur, binned);
    k_scatter<<<NBTOT, 512, 0, stream>>>(gcur, binned, offsets);
    k_topk<<<4, 1024, 0, stream>>>(scores, x, xtT);

    for (int t = 0; t < 4; ++t) {
        const float* WprevT = (t == 0) ? Wst : (Wst + ((t + 1) & 1) * 32768);
        float* WnextT = Wst + (t & 1) * 32768;
        k_gru<<<64, 256, 0, stream>>>(xtT + t * 32768, WprevT, W0, (t == 0) ? 1 : 0, Tp,
                                      bz, br, bh, WnextT, WnT + t * 32768);
    }
    k_gemm<<<dim3(313, 4), 128, 0, stream>>>(xb16, WnT, y);
    k_agg<<<N_, 256, 0, stream>>>(offsets, binned, y, out);
}